// Round 1
// baseline (2083.669 us; speedup 1.0000x reference)
//
#include <hip/hip_runtime.h>
#include <cstdint>

#define N_PTS   8192
#define N_BATCH 8
#define NPOINT  2048
#define NSAMPLE 32
#define C_FEAT  64
#define R2      0.04f
#define FPS_T   512
#define PPT     (N_PTS / FPS_T)   // 16 points per thread

// ---------------------------------------------------------------------------
// Kernel 1: farthest point sampling, one block per batch.
// Emits new_xyz[b][it] = xyz[b][far_it] directly (fps indices never needed
// downstream beyond the coordinates).
// Argmax key: ((u64)f32bits(dist) << 32) | (0xFFFFFFFF - idx), reduced with
// fmax on doubles (all keys are positive, so f64 max == u64 max) -> max dist,
// ties broken toward smallest index (first-occurrence, matching jnp.argmax).
// ---------------------------------------------------------------------------
__global__ __launch_bounds__(FPS_T) void fps_kernel(const float* __restrict__ xyz,
                                                    float* __restrict__ new_xyz) {
  __shared__ float sx[N_PTS];
  __shared__ float sy[N_PTS];
  __shared__ float sz[N_PTS];
  __shared__ double pkey[2][FPS_T / 64];

  const int b = blockIdx.x;
  const int t = threadIdx.x;
  const float* xb = xyz + (size_t)b * N_PTS * 3;

  // Stage xyz for this batch into LDS (one-time).
  for (int e = t; e < N_PTS * 3; e += FPS_T) {
    float v = xb[e];
    int p = e / 3;
    int c = e - 3 * p;
    if (c == 0) sx[p] = v;
    else if (c == 1) sy[p] = v;
    else sz[p] = v;
  }
  __syncthreads();

  // Per-thread points in registers (strided ownership: point k*512 + t).
  float px[PPT], py[PPT], pz[PPT], dist[PPT];
  uint32_t lokey[PPT];
#pragma unroll
  for (int k = 0; k < PPT; ++k) {
    int p = k * FPS_T + t;
    px[k] = sx[p];
    py[k] = sy[p];
    pz[k] = sz[p];
    dist[k] = __builtin_inff();
    lokey[k] = 0xFFFFFFFFu - (uint32_t)p;
  }

  int far = 0;
  for (int it = 0; it < NPOINT; ++it) {
    // Emit current selection (scan emits far BEFORE the update).
    float cx = sx[far], cy = sy[far], cz = sz[far];
    if (t == 0) {
      float* o = new_xyz + ((size_t)b * NPOINT + it) * 3;
      o[0] = cx; o[1] = cy; o[2] = cz;
    }

    // dist update + packed argmax accumulation.
    double bestkey = 0.0;
    {
#pragma clang fp contract(off)
#pragma unroll
      for (int k = 0; k < PPT; ++k) {
        float dx = px[k] - cx;
        float a = dx * dx;
        float dy = py[k] - cy;
        a = a + dy * dy;            // exact left-to-right, no FMA
        float dz = pz[k] - cz;
        a = a + dz * dz;
        float d = fminf(dist[k], a);
        dist[k] = d;
        uint64_t kb = ((uint64_t)__builtin_bit_cast(uint32_t, d) << 32) | (uint64_t)lokey[k];
        double dk = __builtin_bit_cast(double, kb);
        bestkey = fmax(bestkey, dk);
      }
    }

    // Wave reduction (64-wide butterfly).
#pragma unroll
    for (int off = 32; off >= 1; off >>= 1) {
      double o = __shfl_xor(bestkey, off, 64);
      bestkey = fmax(bestkey, o);
    }
    if ((t & 63) == 0) pkey[it & 1][t >> 6] = bestkey;
    __syncthreads();

    double w = pkey[it & 1][0];
#pragma unroll
    for (int i = 1; i < FPS_T / 64; ++i) w = fmax(w, pkey[it & 1][i]);
    far = (int)(0xFFFFFFFFu - (uint32_t)__builtin_bit_cast(uint64_t, w));
  }
}

// ---------------------------------------------------------------------------
// Kernel 2: ball query + gather + concat, one wave per query.
// Scans points in index order, collects first 32 in-ball indices (strict
// dist2 < r^2, exact left-to-right fp32 sum, no FMA), pads with the first
// in-ball index, then writes the 32x67 output tile fully coalesced.
// ---------------------------------------------------------------------------
__global__ __launch_bounds__(256) void ball_group_kernel(const float* __restrict__ xyz,
                                                         const float* __restrict__ points,
                                                         const float* __restrict__ new_xyz,
                                                         float* __restrict__ out_np) {
  __shared__ int list[4][NSAMPLE];
  const int wslot = threadIdx.x >> 6;
  const int lane = threadIdx.x & 63;
  const int qg = blockIdx.x * 4 + wslot;      // global query id, 0..16383
  const int b = qg >> 11;                     // 2048 queries per batch

  const float* xb = xyz + (size_t)b * N_PTS * 3;
  const float* nq = new_xyz + (size_t)qg * 3;
  const float cqx = nq[0], cqy = nq[1], cqz = nq[2];

  int K = 0;
  {
#pragma clang fp contract(off)
    for (int c = 0; c < N_PTS / 64; ++c) {
      const int pt = c * 64 + lane;
      const float* p = xb + pt * 3;
      float dx = cqx - p[0];
      float dy = cqy - p[1];
      float dz = cqz - p[2];
      float d2 = dx * dx;
      d2 = d2 + dy * dy;
      d2 = d2 + dz * dz;
      bool in = d2 < R2;
      unsigned long long mask = __ballot(in);
      if (in) {
        int rank = __builtin_amdgcn_mbcnt_hi((uint32_t)(mask >> 32),
                     __builtin_amdgcn_mbcnt_lo((uint32_t)mask, 0));
        int s = K + rank;
        if (s < NSAMPLE) list[wslot][s] = pt;
      }
      K += (int)__popcll(mask);
      if (K >= NSAMPLE) break;   // wave-uniform
    }
  }
  __builtin_amdgcn_wave_barrier();
  // Pad remaining slots with the first in-ball index (always >=1: the query
  // point itself is an exact copy of an xyz row -> dist2 == 0 < r^2).
  int Kc = K < NSAMPLE ? K : NSAMPLE;
  int first = list[wslot][0];
  if (lane >= Kc && lane < NSAMPLE) list[wslot][lane] = first;
  __builtin_amdgcn_wave_barrier();

  // Output: 32 slots x 67 feats = 2144 contiguous floats per query.
  const float* pb = points + (size_t)b * N_PTS * C_FEAT;
  float* oq = out_np + (size_t)qg * (NSAMPLE * 67);
  for (int r = 0; r < 34; ++r) {
    int tt = r * 64 + lane;
    if (tt < NSAMPLE * 67) {
      int s = tt / 67;
      int f = tt - s * 67;
      int idx = list[wslot][s];
      float val;
      if (f < 3) {
        float cf = (f == 0) ? cqx : ((f == 1) ? cqy : cqz);
        val = xb[idx * 3 + f] - cf;
      } else {
        val = pb[(size_t)idx * C_FEAT + (f - 3)];
      }
      oq[tt] = val;
    }
  }
}

extern "C" void kernel_launch(void* const* d_in, const int* in_sizes, int n_in,
                              void* d_out, int out_size, void* d_ws, size_t ws_size,
                              hipStream_t stream) {
  const float* xyz = (const float*)d_in[0];     // (8, 8192, 3) f32
  const float* points = (const float*)d_in[1];  // (8, 8192, 64) f32
  float* out = (float*)d_out;
  float* new_xyz = out;                                    // (8, 2048, 3)
  float* new_points = out + (size_t)N_BATCH * NPOINT * 3;  // (8, 2048, 32, 67)

  fps_kernel<<<N_BATCH, FPS_T, 0, stream>>>(xyz, new_xyz);
  ball_group_kernel<<<(N_BATCH * NPOINT) / 4, 256, 0, stream>>>(xyz, points, new_xyz, new_points);
}

// Round 2
// 1810.852 us; speedup vs baseline: 1.1507x; 1.1507x over previous
//
#include <hip/hip_runtime.h>
#include <cstdint>

#define N_PTS   8192
#define N_BATCH 8
#define NPOINT  2048
#define NSAMPLE 32
#define C_FEAT  64
#define R2      0.04f
#define FPS_T   512
#define CH      16          // points per thread = one chunk
#define NBINS   512         // 9-bit morton (3 bits/axis)

static __device__ __forceinline__ uint32_t spread3(uint32_t v) {
  // 3 bits -> bit positions 0,3,6
  return (v & 1u) | ((v & 2u) << 2) | ((v & 4u) << 4);
}

static __device__ __forceinline__ uint32_t cell_of(float x, float y, float z) {
  int ix = (int)(x * 8.0f); ix = ix < 0 ? 0 : (ix > 7 ? 7 : ix);
  int iy = (int)(y * 8.0f); iy = iy < 0 ? 0 : (iy > 7 ? 7 : iy);
  int iz = (int)(z * 8.0f); iz = iz < 0 ? 0 : (iz > 7 ? 7 : iz);
  return spread3((uint32_t)ix) | (spread3((uint32_t)iy) << 1) | (spread3((uint32_t)iz) << 2);
}

// One butterfly-free wave-max step on a packed positive f64 key via DPP moves
// (two b32 halves move with the same pattern; shifted-in lanes read 0 -> 0.0,
// harmless for max since all real keys > 0). Result lands in lane 63.
#define DPP_MAXD(v, CTRL) do {                                                          \
  uint64_t u_ = __builtin_bit_cast(uint64_t, v);                                        \
  int lo_ = __builtin_amdgcn_update_dpp(0, (int)(uint32_t)u_,         CTRL, 0xF, 0xF, true); \
  int hi_ = __builtin_amdgcn_update_dpp(0, (int)(uint32_t)(u_ >> 32), CTRL, 0xF, 0xF, true); \
  double p_ = __builtin_bit_cast(double, ((uint64_t)(uint32_t)hi_ << 32) | (uint64_t)(uint32_t)lo_); \
  v = __builtin_fmax(v, p_);                                                            \
} while (0)

// ---------------------------------------------------------------------------
// FPS with exact bbox pruning. One block per batch.
// Key = ((u64)f32bits(maxdist) << 32) | (0xFFFFFFFF - minidx); f64 max == u64
// max for positive doubles -> max dist with first-occurrence (min idx) ties.
// ---------------------------------------------------------------------------
__global__ __launch_bounds__(FPS_T) void fps_kernel(const float* __restrict__ xyz,
                                                    float* __restrict__ new_xyz) {
  __shared__ float sx[N_PTS], sy[N_PTS], sz[N_PTS];   // original index order
  __shared__ int perm[N_PTS];
  __shared__ uint32_t bins[NBINS];
  __shared__ double pkey[2][FPS_T / 64];

  const int b = blockIdx.x;
  const int t = threadIdx.x;
  const int lane = t & 63;
  const int w = t >> 6;
  const float* xb = xyz + (size_t)b * N_PTS * 3;

  // ---- setup: stage coords ----
  for (int e = t; e < N_PTS * 3; e += FPS_T) {
    float v = xb[e];
    int p = e / 3, c = e - 3 * p;
    if (c == 0) sx[p] = v;
    else if (c == 1) sy[p] = v;
    else sz[p] = v;
  }
  bins[t] = 0;            // FPS_T == NBINS
  __syncthreads();

  // ---- counting sort by morton cell: histogram ----
#pragma unroll
  for (int k = 0; k < CH; ++k) {
    int p = k * FPS_T + t;
    atomicAdd(&bins[cell_of(sx[p], sy[p], sz[p])], 1u);
  }
  __syncthreads();

  // ---- exclusive scan of 512 bins (wave 0, in place) ----
  if (t < 64) {
    uint32_t v[8], e[8], run = 0;
#pragma unroll
    for (int j = 0; j < 8; ++j) v[j] = bins[t * 8 + j];
#pragma unroll
    for (int j = 0; j < 8; ++j) { e[j] = run; run += v[j]; }
    uint32_t inc = run;
#pragma unroll
    for (int off = 1; off < 64; off <<= 1) {
      uint32_t o = __shfl_up(inc, off, 64);
      if (t >= off) inc += o;
    }
    uint32_t base = inc - run;
#pragma unroll
    for (int j = 0; j < 8; ++j) bins[t * 8 + j] = base + e[j];
  }
  __syncthreads();

  // ---- scatter permutation ----
#pragma unroll
  for (int k = 0; k < CH; ++k) {
    int p = k * FPS_T + t;
    uint32_t pos = atomicAdd(&bins[cell_of(sx[p], sy[p], sz[p])], 1u);
    perm[pos] = p;
  }
  __syncthreads();

  // ---- load chunk into registers, compute bbox ----
  float rx[CH], ry[CH], rz[CH], dist[CH];
  uint32_t ridx[CH];
#pragma unroll
  for (int j = 0; j < CH; ++j) {
    int p = perm[CH * t + j];
    ridx[j] = (uint32_t)p;
    rx[j] = sx[p]; ry[j] = sy[p]; rz[j] = sz[p];
    dist[j] = __builtin_inff();
  }
  float bnx = rx[0], bxx = rx[0], bny = ry[0], bxy = ry[0], bnz = rz[0], bxz = rz[0];
#pragma unroll
  for (int j = 1; j < CH; ++j) {
    bnx = fminf(bnx, rx[j]); bxx = fmaxf(bxx, rx[j]);
    bny = fminf(bny, ry[j]); bxy = fmaxf(bxy, ry[j]);
    bnz = fminf(bnz, rz[j]); bxz = fmaxf(bxz, rz[j]);
  }

  float cmax = __builtin_inff();   // chunk max dist (cached)
  uint32_t cidx = 0;               // chunk argmax orig idx (cached)
  int far = 0;

  for (int it = 0; it < NPOINT; ++it) {
    float cx = sx[far], cy = sy[far], cz = sz[far];
    if (t == 0) {
      float* o = new_xyz + ((size_t)b * NPOINT + it) * 3;
      o[0] = cx; o[1] = cy; o[2] = cz;
    }

    // conservative lower bound of any d2 in this chunk (margin 1e-5 >> fp err)
    float gx = fmaxf(fmaxf(bnx - cx, cx - bxx), 0.0f);
    float gy = fmaxf(fmaxf(bny - cy, cy - bxy), 0.0f);
    float gz = fmaxf(fmaxf(bnz - cz, cz - bxz), 0.0f);
    float lb = gx * gx + gy * gy + gz * gz;

    if (!(lb * 0.99999f >= cmax)) {
      // update all 16 points: EXACT left-to-right fp32, no FMA
      {
#pragma clang fp contract(off)
#pragma unroll
        for (int j = 0; j < CH; ++j) {
          float dx = rx[j] - cx;
          float a = dx * dx;
          float dy = ry[j] - cy;
          a = a + dy * dy;
          float dz = rz[j] - cz;
          a = a + dz * dz;
          dist[j] = fminf(dist[j], a);
        }
      }
      // recompute chunk max (tree) + first-occurrence tie index
      float m0 = fmaxf(dist[0], dist[1]),  m1 = fmaxf(dist[2], dist[3]);
      float m2 = fmaxf(dist[4], dist[5]),  m3 = fmaxf(dist[6], dist[7]);
      float m4 = fmaxf(dist[8], dist[9]),  m5 = fmaxf(dist[10], dist[11]);
      float m6 = fmaxf(dist[12], dist[13]), m7 = fmaxf(dist[14], dist[15]);
      m0 = fmaxf(m0, m1); m2 = fmaxf(m2, m3); m4 = fmaxf(m4, m5); m6 = fmaxf(m6, m7);
      cmax = fmaxf(fmaxf(m0, m2), fmaxf(m4, m6));
      uint32_t mi = 0xFFFFFFFFu;
#pragma unroll
      for (int j = 0; j < CH; ++j) {
        uint32_t cand = ridx[j] < mi ? ridx[j] : mi;
        mi = (dist[j] == cmax) ? cand : mi;
      }
      cidx = mi;
    }

    double key = __builtin_bit_cast(double,
        ((uint64_t)__builtin_bit_cast(uint32_t, cmax) << 32) |
        (uint64_t)(0xFFFFFFFFu - cidx));

    // wave max via DPP: row_shr 1/2/4/8 then row_bcast 15/31 -> lane 63
    DPP_MAXD(key, 0x111);
    DPP_MAXD(key, 0x112);
    DPP_MAXD(key, 0x114);
    DPP_MAXD(key, 0x118);
    DPP_MAXD(key, 0x142);
    DPP_MAXD(key, 0x143);
    if (lane == 63) pkey[it & 1][w] = key;
    __syncthreads();

    const double* pk = pkey[it & 1];
    double g01 = __builtin_fmax(pk[0], pk[1]);
    double g23 = __builtin_fmax(pk[2], pk[3]);
    double g45 = __builtin_fmax(pk[4], pk[5]);
    double g67 = __builtin_fmax(pk[6], pk[7]);
    double g = __builtin_fmax(__builtin_fmax(g01, g23), __builtin_fmax(g45, g67));
    far = (int)(0xFFFFFFFFu - (uint32_t)__builtin_bit_cast(uint64_t, g));
  }
}

// ---------------------------------------------------------------------------
// Ball query + gather + concat, one wave per query (unchanged from round 1).
// ---------------------------------------------------------------------------
__global__ __launch_bounds__(256) void ball_group_kernel(const float* __restrict__ xyz,
                                                         const float* __restrict__ points,
                                                         const float* __restrict__ new_xyz,
                                                         float* __restrict__ out_np) {
  __shared__ int list[4][NSAMPLE];
  const int wslot = threadIdx.x >> 6;
  const int lane = threadIdx.x & 63;
  const int qg = blockIdx.x * 4 + wslot;
  const int b = qg >> 11;

  const float* xb = xyz + (size_t)b * N_PTS * 3;
  const float* nq = new_xyz + (size_t)qg * 3;
  const float cqx = nq[0], cqy = nq[1], cqz = nq[2];

  int K = 0;
  {
#pragma clang fp contract(off)
    for (int c = 0; c < N_PTS / 64; ++c) {
      const int pt = c * 64 + lane;
      const float* p = xb + pt * 3;
      float dx = cqx - p[0];
      float dy = cqy - p[1];
      float dz = cqz - p[2];
      float d2 = dx * dx;
      d2 = d2 + dy * dy;
      d2 = d2 + dz * dz;
      bool in = d2 < R2;
      unsigned long long mask = __ballot(in);
      if (in) {
        int rank = __builtin_amdgcn_mbcnt_hi((uint32_t)(mask >> 32),
                     __builtin_amdgcn_mbcnt_lo((uint32_t)mask, 0));
        int s = K + rank;
        if (s < NSAMPLE) list[wslot][s] = pt;
      }
      K += (int)__popcll(mask);
      if (K >= NSAMPLE) break;   // wave-uniform
    }
  }
  __builtin_amdgcn_wave_barrier();
  int Kc = K < NSAMPLE ? K : NSAMPLE;
  int first = list[wslot][0];
  if (lane >= Kc && lane < NSAMPLE) list[wslot][lane] = first;
  __builtin_amdgcn_wave_barrier();

  const float* pb = points + (size_t)b * N_PTS * C_FEAT;
  float* oq = out_np + (size_t)qg * (NSAMPLE * 67);
  for (int r = 0; r < 34; ++r) {
    int tt = r * 64 + lane;
    if (tt < NSAMPLE * 67) {
      int s = tt / 67;
      int f = tt - s * 67;
      int idx = list[wslot][s];
      float val;
      if (f < 3) {
        float cf = (f == 0) ? cqx : ((f == 1) ? cqy : cqz);
        val = xb[idx * 3 + f] - cf;
      } else {
        val = pb[(size_t)idx * C_FEAT + (f - 3)];
      }
      oq[tt] = val;
    }
  }
}

extern "C" void kernel_launch(void* const* d_in, const int* in_sizes, int n_in,
                              void* d_out, int out_size, void* d_ws, size_t ws_size,
                              hipStream_t stream) {
  const float* xyz = (const float*)d_in[0];
  const float* points = (const float*)d_in[1];
  float* out = (float*)d_out;
  float* new_xyz = out;
  float* new_points = out + (size_t)N_BATCH * NPOINT * 3;

  fps_kernel<<<N_BATCH, FPS_T, 0, stream>>>(xyz, new_xyz);
  ball_group_kernel<<<(N_BATCH * NPOINT) / 4, 256, 0, stream>>>(xyz, points, new_xyz, new_points);
}

// Round 3
// 1752.597 us; speedup vs baseline: 1.1889x; 1.0332x over previous
//
#include <hip/hip_runtime.h>
#include <cstdint>

#define N_PTS   8192
#define N_BATCH 8
#define NPOINT  2048
#define NSAMPLE 32
#define C_FEAT  64
#define R2      0.04f
#define FPS_T   512
#define CH      16          // points per thread = one chunk
#define NBINS   512         // 9-bit morton (3 bits/axis)

static __device__ __forceinline__ uint32_t spread3(uint32_t v) {
  return (v & 1u) | ((v & 2u) << 2) | ((v & 4u) << 4);
}

static __device__ __forceinline__ uint32_t cell_of(float x, float y, float z) {
  int ix = (int)(x * 8.0f); ix = ix < 0 ? 0 : (ix > 7 ? 7 : ix);
  int iy = (int)(y * 8.0f); iy = iy < 0 ? 0 : (iy > 7 ? 7 : iy);
  int iz = (int)(z * 8.0f); iz = iz < 0 ? 0 : (iz > 7 ? 7 : iz);
  return spread3((uint32_t)ix) | (spread3((uint32_t)iy) << 1) | (spread3((uint32_t)iz) << 2);
}

// Wave-max step on packed positive f64 key via DPP (verified exact in R2).
#define DPP_MAXD(v, CTRL) do {                                                          \
  uint64_t u_ = __builtin_bit_cast(uint64_t, v);                                        \
  int lo_ = __builtin_amdgcn_update_dpp(0, (int)(uint32_t)u_,         CTRL, 0xF, 0xF, true); \
  int hi_ = __builtin_amdgcn_update_dpp(0, (int)(uint32_t)(u_ >> 32), CTRL, 0xF, 0xF, true); \
  double p_ = __builtin_bit_cast(double, ((uint64_t)(uint32_t)hi_ << 32) | (uint64_t)(uint32_t)lo_); \
  v = __builtin_fmax(v, p_);                                                            \
} while (0)

// ---------------------------------------------------------------------------
// FPS with exact bbox pruning. One block per batch. NO global memory ops in
// the iteration loop: centroids staged in LDS (aliasing dead perm buffer),
// written out once at the end. Key = (f32bits(maxdist)<<32)|(~minidx), f64
// max == u64 max for positive keys -> max dist, first-occurrence ties.
// ---------------------------------------------------------------------------
__global__ __launch_bounds__(FPS_T) void fps_kernel(const float* __restrict__ xyz,
                                                    float* __restrict__ new_xyz) {
  __shared__ float sx[N_PTS], sy[N_PTS], sz[N_PTS];   // original index order
  __shared__ int perm[N_PTS];          // setup only; reused as cent[] in loop
  __shared__ uint32_t bins[NBINS];
  __shared__ double pkey[2][FPS_T / 64];
  float* cent = (float*)perm;          // [NPOINT*3] = 24 KB < 32 KB

  const int b = blockIdx.x;
  const int t = threadIdx.x;
  const int lane = t & 63;
  const int w = t >> 6;
  const float* xb = xyz + (size_t)b * N_PTS * 3;

  // ---- setup: stage coords ----
  for (int e = t; e < N_PTS * 3; e += FPS_T) {
    float v = xb[e];
    int p = e / 3, c = e - 3 * p;
    if (c == 0) sx[p] = v;
    else if (c == 1) sy[p] = v;
    else sz[p] = v;
  }
  bins[t] = 0;            // FPS_T == NBINS
  __syncthreads();

  // ---- counting sort by morton cell: histogram ----
#pragma unroll
  for (int k = 0; k < CH; ++k) {
    int p = k * FPS_T + t;
    atomicAdd(&bins[cell_of(sx[p], sy[p], sz[p])], 1u);
  }
  __syncthreads();

  // ---- exclusive scan of 512 bins (wave 0, in place) ----
  if (t < 64) {
    uint32_t v[8], e[8], run = 0;
#pragma unroll
    for (int j = 0; j < 8; ++j) v[j] = bins[t * 8 + j];
#pragma unroll
    for (int j = 0; j < 8; ++j) { e[j] = run; run += v[j]; }
    uint32_t inc = run;
#pragma unroll
    for (int off = 1; off < 64; off <<= 1) {
      uint32_t o = __shfl_up(inc, off, 64);
      if (t >= off) inc += o;
    }
    uint32_t base = inc - run;
#pragma unroll
    for (int j = 0; j < 8; ++j) bins[t * 8 + j] = base + e[j];
  }
  __syncthreads();

  // ---- scatter permutation ----
#pragma unroll
  for (int k = 0; k < CH; ++k) {
    int p = k * FPS_T + t;
    uint32_t pos = atomicAdd(&bins[cell_of(sx[p], sy[p], sz[p])], 1u);
    perm[pos] = p;
  }
  __syncthreads();

  // ---- load chunk into registers, compute bbox ----
  float rx[CH], ry[CH], rz[CH], dist[CH];
  uint32_t ridx[CH];
#pragma unroll
  for (int j = 0; j < CH; ++j) {
    int p = perm[CH * t + j];
    ridx[j] = (uint32_t)p;
    rx[j] = sx[p]; ry[j] = sy[p]; rz[j] = sz[p];
    dist[j] = __builtin_inff();
  }
  float bnx = rx[0], bxx = rx[0], bny = ry[0], bxy = ry[0], bnz = rz[0], bxz = rz[0];
#pragma unroll
  for (int j = 1; j < CH; ++j) {
    bnx = fminf(bnx, rx[j]); bxx = fmaxf(bxx, rx[j]);
    bny = fminf(bny, ry[j]); bxy = fmaxf(bxy, ry[j]);
    bnz = fminf(bnz, rz[j]); bxz = fmaxf(bxz, rz[j]);
  }
  __syncthreads();   // perm fully consumed; cent alias is now safe

  float cmax = __builtin_inff();   // chunk max dist (cached)
  uint32_t cidx = 0;               // chunk argmax orig idx (cached)
  int far = 0;

  for (int it = 0; it < NPOINT; ++it) {
    float cx = sx[far], cy = sy[far], cz = sz[far];
    if (t == 0) {   // LDS staging only -- no global store in the loop
      cent[it * 3 + 0] = cx;
      cent[it * 3 + 1] = cy;
      cent[it * 3 + 2] = cz;
    }

    // conservative lower bound of any d2 in this chunk (margin 1e-5 >> fp err)
    float gx = fmaxf(fmaxf(bnx - cx, cx - bxx), 0.0f);
    float gy = fmaxf(fmaxf(bny - cy, cy - bxy), 0.0f);
    float gz = fmaxf(fmaxf(bnz - cz, cz - bxz), 0.0f);
    float lb = gx * gx + gy * gy + gz * gz;

    if (!(lb * 0.99999f >= cmax)) {
      {
#pragma clang fp contract(off)
#pragma unroll
        for (int j = 0; j < CH; ++j) {
          float dx = rx[j] - cx;
          float a = dx * dx;
          float dy = ry[j] - cy;
          a = a + dy * dy;
          float dz = rz[j] - cz;
          a = a + dz * dz;
          dist[j] = fminf(dist[j], a);
        }
      }
      float m0 = fmaxf(dist[0], dist[1]),  m1 = fmaxf(dist[2], dist[3]);
      float m2 = fmaxf(dist[4], dist[5]),  m3 = fmaxf(dist[6], dist[7]);
      float m4 = fmaxf(dist[8], dist[9]),  m5 = fmaxf(dist[10], dist[11]);
      float m6 = fmaxf(dist[12], dist[13]), m7 = fmaxf(dist[14], dist[15]);
      m0 = fmaxf(m0, m1); m2 = fmaxf(m2, m3); m4 = fmaxf(m4, m5); m6 = fmaxf(m6, m7);
      cmax = fmaxf(fmaxf(m0, m2), fmaxf(m4, m6));
      uint32_t mi = 0xFFFFFFFFu;
#pragma unroll
      for (int j = 0; j < CH; ++j) {
        uint32_t cand = ridx[j] < mi ? ridx[j] : mi;
        mi = (dist[j] == cmax) ? cand : mi;
      }
      cidx = mi;
    }

    double key = __builtin_bit_cast(double,
        ((uint64_t)__builtin_bit_cast(uint32_t, cmax) << 32) |
        (uint64_t)(0xFFFFFFFFu - cidx));

    DPP_MAXD(key, 0x111);   // row_shr 1
    DPP_MAXD(key, 0x112);   // row_shr 2
    DPP_MAXD(key, 0x114);   // row_shr 4
    DPP_MAXD(key, 0x118);   // row_shr 8
    DPP_MAXD(key, 0x142);   // row_bcast 15
    DPP_MAXD(key, 0x143);   // row_bcast 31
    if (lane == 63) pkey[it & 1][w] = key;
    __syncthreads();

    const double* pk = pkey[it & 1];
    double g01 = __builtin_fmax(pk[0], pk[1]);
    double g23 = __builtin_fmax(pk[2], pk[3]);
    double g45 = __builtin_fmax(pk[4], pk[5]);
    double g67 = __builtin_fmax(pk[6], pk[7]);
    double g = __builtin_fmax(__builtin_fmax(g01, g23), __builtin_fmax(g45, g67));
    far = (int)(0xFFFFFFFFu - (uint32_t)__builtin_bit_cast(uint64_t, g));
  }

  // ---- one-time coalesced copy-out of staged centroids ----
  __syncthreads();
  float* ob = new_xyz + (size_t)b * NPOINT * 3;
  for (int e = t; e < NPOINT * 3; e += FPS_T) ob[e] = cent[e];
}

// ---------------------------------------------------------------------------
// Ball query + gather + concat, one wave per query (unchanged, verified).
// ---------------------------------------------------------------------------
__global__ __launch_bounds__(256) void ball_group_kernel(const float* __restrict__ xyz,
                                                         const float* __restrict__ points,
                                                         const float* __restrict__ new_xyz,
                                                         float* __restrict__ out_np) {
  __shared__ int list[4][NSAMPLE];
  const int wslot = threadIdx.x >> 6;
  const int lane = threadIdx.x & 63;
  const int qg = blockIdx.x * 4 + wslot;
  const int b = qg >> 11;

  const float* xb = xyz + (size_t)b * N_PTS * 3;
  const float* nq = new_xyz + (size_t)qg * 3;
  const float cqx = nq[0], cqy = nq[1], cqz = nq[2];

  int K = 0;
  {
#pragma clang fp contract(off)
    for (int c = 0; c < N_PTS / 64; ++c) {
      const int pt = c * 64 + lane;
      const float* p = xb + pt * 3;
      float dx = cqx - p[0];
      float dy = cqy - p[1];
      float dz = cqz - p[2];
      float d2 = dx * dx;
      d2 = d2 + dy * dy;
      d2 = d2 + dz * dz;
      bool in = d2 < R2;
      unsigned long long mask = __ballot(in);
      if (in) {
        int rank = __builtin_amdgcn_mbcnt_hi((uint32_t)(mask >> 32),
                     __builtin_amdgcn_mbcnt_lo((uint32_t)mask, 0));
        int s = K + rank;
        if (s < NSAMPLE) list[wslot][s] = pt;
      }
      K += (int)__popcll(mask);
      if (K >= NSAMPLE) break;   // wave-uniform
    }
  }
  __builtin_amdgcn_wave_barrier();
  int Kc = K < NSAMPLE ? K : NSAMPLE;
  int first = list[wslot][0];
  if (lane >= Kc && lane < NSAMPLE) list[wslot][lane] = first;
  __builtin_amdgcn_wave_barrier();

  const float* pb = points + (size_t)b * N_PTS * C_FEAT;
  float* oq = out_np + (size_t)qg * (NSAMPLE * 67);
  for (int r = 0; r < 34; ++r) {
    int tt = r * 64 + lane;
    if (tt < NSAMPLE * 67) {
      int s = tt / 67;
      int f = tt - s * 67;
      int idx = list[wslot][s];
      float val;
      if (f < 3) {
        float cf = (f == 0) ? cqx : ((f == 1) ? cqy : cqz);
        val = xb[idx * 3 + f] - cf;
      } else {
        val = pb[(size_t)idx * C_FEAT + (f - 3)];
      }
      oq[tt] = val;
    }
  }
}

extern "C" void kernel_launch(void* const* d_in, const int* in_sizes, int n_in,
                              void* d_out, int out_size, void* d_ws, size_t ws_size,
                              hipStream_t stream) {
  const float* xyz = (const float*)d_in[0];
  const float* points = (const float*)d_in[1];
  float* out = (float*)d_out;
  float* new_xyz = out;
  float* new_points = out + (size_t)N_BATCH * NPOINT * 3;

  fps_kernel<<<N_BATCH, FPS_T, 0, stream>>>(xyz, new_xyz);
  ball_group_kernel<<<(N_BATCH * NPOINT) / 4, 256, 0, stream>>>(xyz, points, new_xyz, new_points);
}